// Round 3
// baseline (1521.229 us; speedup 1.0000x reference)
//
#include <hip/hip_runtime.h>
#include <hip/hip_cooperative_groups.h>
#include <math.h>

namespace cg = cooperative_groups;

// Problem constants: B=16, K=6 kernels (+1 text channel), H=W=640
#define BB   16
#define KCH  6
#define CH   7
#define NN   409600
#define N4   102400          // float4 per plane
#define BINS 65536
#define EPSF 1e-6f
#define GRID 1024            // 4 blocks/CU x 256 CUs (co-resident for coop launch)

// ---- workspace layout (32-bit word offsets) ----
#define HIST_WORDS (BB * BINS)            // 1,048,576 words = 4 MB
#define SMALL_OFF  HIST_WORDS
#define POS_OFF   (SMALL_OFF + 0)
#define NEGT_OFF  (SMALL_OFF + 16)
#define PRE_OFF   (SMALL_OFF + 32)
#define RANK_OFF  (SMALL_OFF + 48)
#define THR_OFF   (SMALL_OFF + 64)
#define UOH_OFF   (SMALL_OFF + 80)
#define TEXT_OFF  (SMALL_OFF + 96)        // BB*3 floats
#define KERN_OFF  (SMALL_OFF + 144)       // BB*KCH*3 floats
#define SMALL_WORDS 432
#define KMASK_OFF (SMALL_OFF + SMALL_WORDS)   // byte array BB*N4 follows

#define PREP_TILES   1600    // 16 planes x 100 tiles of 1024 float4
#define DICE_TTILES  800     // 16 planes x 50 tiles of 2048 float4
#define DICE_KTILES  4800    // 96 planes x 50 tiles of 2048 float4
#define DICE_TILES   (DICE_TTILES + DICE_KTILES)

__device__ __forceinline__ unsigned sortkey(float f) {
    unsigned u = __float_as_uint(f);
    return (u & 0x80000000u) ? ~u : (u | 0x80000000u);
}
__device__ __forceinline__ float sig(float x) {
    return __builtin_amdgcn_rcpf(1.0f + __expf(-x));
}
__device__ __forceinline__ float wred(float v) {
#pragma unroll
    for (int o = 32; o > 0; o >>= 1) v += __shfl_down(v, o, 64);
    return v;
}
__device__ __forceinline__ unsigned wredu(unsigned v) {
#pragma unroll
    for (int o = 32; o > 0; o >>= 1) v += __shfl_down(v, o, 64);
    return v;
}

// ---------------- phase bodies (shared by coop kernel and fallback kernels) --------------

__device__ __forceinline__ void prep_elem(float pf, float gf, float mf, int s,
                                          unsigned& lpos, unsigned& lneg, unsigned& mb,
                                          unsigned* hist) {
    bool neg = (gf <= 0.5f);
    lneg += neg ? 1u : 0u;
    lpos += (gf > 0.5f && mf > 0.5f) ? 1u : 0u;
    if (neg) atomicAdd(&hist[sortkey(pf) >> 16], 1u);
    if (pf > 0.f && mf > 0.5f) mb |= (1u << s);
}

__device__ void prep_tile(int tile, const float* __restrict__ pred,
                          const float* __restrict__ gt, const float* __restrict__ tm,
                          unsigned* __restrict__ ws, unsigned char* __restrict__ kmask, int t) {
    const int b   = tile / 100;
    const int off = (tile % 100) * 1024;
    const float4* p4 = (const float4*)(pred + ((size_t)b * CH + KCH) * NN) + off;
    const float4* g4 = (const float4*)(gt + (size_t)b * NN) + off;
    const float4* m4 = (const float4*)(tm + (size_t)b * NN) + off;
    unsigned char* km = kmask + (size_t)b * N4 + off;
    unsigned* hist = ws + (size_t)b * BINS;

    unsigned lpos = 0, lneg = 0;
    float4 p = p4[t], g = g4[t], m = m4[t];
#pragma unroll
    for (int j = 0; j < 4; j++) {
        float4 pn, gn, mn;
        if (j < 3) { pn = p4[(j + 1) * 256 + t]; gn = g4[(j + 1) * 256 + t]; mn = m4[(j + 1) * 256 + t]; }
        unsigned mb = 0;
        prep_elem(p.x, g.x, m.x, 0, lpos, lneg, mb, hist);
        prep_elem(p.y, g.y, m.y, 1, lpos, lneg, mb, hist);
        prep_elem(p.z, g.z, m.z, 2, lpos, lneg, mb, hist);
        prep_elem(p.w, g.w, m.w, 3, lpos, lneg, mb, hist);
        km[j * 256 + t] = (unsigned char)mb;
        if (j < 3) { p = pn; g = gn; m = mn; }
    }
    lpos = wredu(lpos); lneg = wredu(lneg);
    if ((t & 63) == 0) {
        atomicAdd(&ws[POS_OFF + b], lpos);
        atomicAdd(&ws[NEGT_OFF + b], lneg);
    }
}

__device__ void refine_tile(int tile, const float* __restrict__ pred,
                            const float* __restrict__ gt, unsigned* __restrict__ ws, int t) {
    const int b   = tile / 100;
    const int off = (tile % 100) * 1024;
    const unsigned prefix = ws[PRE_OFF + b];
    const float4* p4 = (const float4*)(pred + ((size_t)b * CH + KCH) * NN) + off;
    const float4* g4 = (const float4*)(gt + (size_t)b * NN) + off;
    unsigned* hist = ws + (size_t)b * BINS;

    float4 p = p4[t], g = g4[t];
#pragma unroll
    for (int j = 0; j < 4; j++) {
        float4 pn, gn;
        if (j < 3) { pn = p4[(j + 1) * 256 + t]; gn = g4[(j + 1) * 256 + t]; }
#pragma unroll
        for (int s = 0; s < 4; s++) {
            float pf = (&p.x)[s], gf = (&g.x)[s];
            if (gf <= 0.5f) {
                unsigned key = sortkey(pf);
                if ((key >> 16) == prefix) atomicAdd(&hist[key & 0xFFFFu], 1u);
            }
        }
        if (j < 3) { p = pn; g = gn; }
    }
}

// Per-batch rank-find over 65536 bins, descending. pass=0: compute neg_num/uoh,
// emit top-16 prefix + residual rank. pass=1: emit final threshold bits.
__device__ void scan_body(unsigned* __restrict__ ws, int b, int t, int pass) {
    __shared__ unsigned seg[256];
    __shared__ unsigned suf[256];
    __shared__ unsigned sbin, srem;
    const unsigned* h = ws + (size_t)b * BINS;
    const uint4* h4 = (const uint4*)(h + t * 256);

    unsigned s = 0;
#pragma unroll 4
    for (int i = 0; i < 64; i++) { uint4 v = h4[i]; s += v.x + v.y + v.z + v.w; }
    seg[t] = s;
    __syncthreads();

    unsigned r;
    if (pass == 0) {
        unsigned pos = ws[POS_OFF + b], ntot = ws[NEGT_OFF + b];
        unsigned negnum = min(3u * pos, ntot);
        if (t == 0) ws[UOH_OFF + b] = (pos > 0u && negnum > 0u) ? 1u : 0u;
        r = (negnum > 0u) ? negnum : 1u;
    } else {
        r = ws[RANK_OFF + b];
    }
    if (t == 0) {
        unsigned acc = 0;
        for (int c = 255; c >= 0; c--) { suf[c] = acc; acc += seg[c]; }
        sbin = 0u; srem = 1u;
    }
    __syncthreads();

    if (r > suf[t] && r <= suf[t] + seg[t]) {
        unsigned cum = suf[t];
        bool done = false;
        for (int i = 63; i >= 0 && !done; i--) {
            uint4 v = h4[i];
            unsigned vals[4] = { v.x, v.y, v.z, v.w };
            for (int q = 3; q >= 0; q--) {
                unsigned c = vals[q];
                if (cum + c >= r) { sbin = (unsigned)(t * 256 + i * 4 + q); srem = r - cum; done = true; break; }
                cum += c;
            }
        }
    }
    __syncthreads();
    if (t == 0) {
        if (pass == 0) {
            ws[PRE_OFF + b] = sbin;
            ws[RANK_OFF + b] = srem;
        } else {
            unsigned key = (ws[PRE_OFF + b] << 16) | sbin;
            unsigned orig = (key & 0x80000000u) ? (key & 0x7FFFFFFFu) : ~key;
            ws[THR_OFF + b] = orig;
        }
    }
}

__device__ void dice_tile(int tile, const float* __restrict__ pred,
                          const float* __restrict__ gt, const float* __restrict__ gtk,
                          const float* __restrict__ tm, unsigned* __restrict__ ws,
                          const unsigned char* __restrict__ kmask, int t) {
    float a0 = 0.f, a1 = 0.f, a2 = 0.f;
    if (tile < DICE_TTILES) {
        const int b   = tile / 50;
        const int off = (tile % 50) * 2048;
        const float thr = __uint_as_float(ws[THR_OFF + b]);
        const bool uoh = (ws[UOH_OFF + b] != 0u);
        const float4* p4 = (const float4*)(pred + ((size_t)b * CH + KCH) * NN) + off;
        const float4* g4 = (const float4*)(gt + (size_t)b * NN) + off;
        const float4* m4 = (const float4*)(tm + (size_t)b * NN) + off;
        float4 p = p4[t], g = g4[t], m = m4[t];
#pragma unroll
        for (int j = 0; j < 8; j++) {
            float4 pn, gn, mn;
            if (j < 7) { pn = p4[(j + 1) * 256 + t]; gn = g4[(j + 1) * 256 + t]; mn = m4[(j + 1) * 256 + t]; }
#pragma unroll
            for (int s = 0; s < 4; s++) {
                float pf = (&p.x)[s], gf = (&g.x)[s], mf = (&m.x)[s];
                float sel = uoh ? (((pf >= thr) || (gf > 0.5f)) && (mf > 0.5f) ? 1.f : 0.f) : mf;
                float pp = sig(pf) * sel;
                float gg = gf * sel;
                a0 += pp * gg; a1 += pp * pp; a2 += gg * gg;
            }
            if (j < 7) { p = pn; g = gn; m = mn; }
        }
        a0 = wred(a0); a1 = wred(a1); a2 = wred(a2);
        float* ts = (float*)(ws + TEXT_OFF);
        if ((t & 63) == 0) {
            atomicAdd(&ts[b * 3 + 0], a0);
            atomicAdd(&ts[b * 3 + 1], a1);
            atomicAdd(&ts[b * 3 + 2], a2);
        }
    } else {
        const int kt    = tile - DICE_TTILES;
        const int plane = kt / 50;                 // b*KCH + k
        const int off   = (kt % 50) * 2048;
        const int b = plane / KCH, k = plane % KCH;
        const float4* pk4 = (const float4*)(pred + ((size_t)b * CH + k) * NN) + off;
        const float4* gk4 = (const float4*)(gtk + (size_t)plane * NN) + off;
        const unsigned char* km = kmask + (size_t)b * N4 + off;
        float4 p = pk4[t], g = gk4[t];
        unsigned char mb = km[t];
#pragma unroll
        for (int j = 0; j < 8; j++) {
            float4 pn, gn; unsigned char mbn = 0;
            if (j < 7) { pn = pk4[(j + 1) * 256 + t]; gn = gk4[(j + 1) * 256 + t]; mbn = km[(j + 1) * 256 + t]; }
#pragma unroll
            for (int s = 0; s < 4; s++) {
                float sel = (float)((mb >> s) & 1u);
                float pf = (&p.x)[s], gf = (&g.x)[s];
                float pp = sig(pf) * sel;
                float gg = gf * sel;
                a0 += pp * gg; a1 += pp * pp; a2 += gg * gg;
            }
            if (j < 7) { p = pn; g = gn; mb = mbn; }
        }
        a0 = wred(a0); a1 = wred(a1); a2 = wred(a2);
        float* kf = (float*)(ws + KERN_OFF);
        if ((t & 63) == 0) {
            atomicAdd(&kf[plane * 3 + 0], a0);
            atomicAdd(&kf[plane * 3 + 1], a1);
            atomicAdd(&kf[plane * 3 + 2], a2);
        }
    }
}

__device__ void final_body(const unsigned* __restrict__ ws, float* __restrict__ out, int t) {
    __shared__ float red[256];
    const float* ts = (const float*)(ws + TEXT_OFF);
    const float* kf = (const float*)(ws + KERN_OFF);
    float v = 0.f;
    if (t < BB) {
        float a = ts[t * 3 + 0], b2 = ts[t * 3 + 1], c = ts[t * 3 + 2];
        v = (1.0f - 2.0f * a / (b2 + c + 2.0f * EPSF)) * (0.7f / BB);
    } else if (t < BB + BB * KCH) {
        int i = t - BB;
        float a = kf[i * 3 + 0], b2 = kf[i * 3 + 1], c = kf[i * 3 + 2];
        v = (1.0f - 2.0f * a / (b2 + c + 2.0f * EPSF)) * (0.3f / (BB * KCH));
    }
    red[t] = v;
    __syncthreads();
    if (t == 0) {
        float s = 0.f;
        for (int i = 0; i < BB + BB * KCH; i++) s += red[i];
        out[0] = s;
    }
}

// ---------------- single cooperative kernel ----------------

__global__ __launch_bounds__(256, 4) void k_all(const float* __restrict__ pred,
                                                const float* __restrict__ gt,
                                                const float* __restrict__ gtk,
                                                const float* __restrict__ tm,
                                                unsigned* __restrict__ ws,
                                                unsigned char* __restrict__ kmask,
                                                float* __restrict__ out) {
    cg::grid_group grid = cg::this_grid();
    const int t = threadIdx.x;
    const int blk = blockIdx.x;

    // phase 0: zero hist + small state
    for (int i = blk * 256 + t; i < HIST_WORDS + SMALL_WORDS; i += GRID * 256) ws[i] = 0u;
    grid.sync();

    // phase 1: counts + top-16 histogram + kmask
    for (int tile = blk; tile < PREP_TILES; tile += GRID) prep_tile(tile, pred, gt, tm, ws, kmask, t);
    grid.sync();

    // phase 2: scan pass 0
    if (blk < BB) scan_body(ws, blk, t, 0);
    grid.sync();

    // phase 3: re-zero hist
    for (int i = blk * 256 + t; i < HIST_WORDS; i += GRID * 256) ws[i] = 0u;
    grid.sync();

    // phase 4: low-16 refine histogram
    for (int tile = blk; tile < PREP_TILES; tile += GRID) refine_tile(tile, pred, gt, ws, t);
    grid.sync();

    // phase 5: scan pass 1 -> threshold
    if (blk < BB) scan_body(ws, blk, t, 1);
    grid.sync();

    // phase 6: fused text + kernel dice partial sums
    for (int tile = blk; tile < DICE_TILES; tile += GRID) dice_tile(tile, pred, gt, gtk, tm, ws, kmask, t);
    grid.sync();

    // phase 7: final scalar
    if (blk == 0) final_body(ws, out, t);
}

// ---------------- fallback discrete kernels (if coop launch unavailable) ----------------

__global__ __launch_bounds__(256) void k_prep_f(const float* pred, const float* gt, const float* tm,
                                                unsigned* ws, unsigned char* kmask) {
    prep_tile(blockIdx.x, pred, gt, tm, ws, kmask, threadIdx.x);
}
__global__ __launch_bounds__(256) void k_refine_f(const float* pred, const float* gt, unsigned* ws) {
    refine_tile(blockIdx.x, pred, gt, ws, threadIdx.x);
}
__global__ __launch_bounds__(256) void k_scan_f(unsigned* ws, int pass) {
    scan_body(ws, blockIdx.x, threadIdx.x, pass);
}
__global__ __launch_bounds__(256) void k_dice_f(const float* pred, const float* gt, const float* gtk,
                                                const float* tm, unsigned* ws, const unsigned char* kmask) {
    dice_tile(blockIdx.x, pred, gt, gtk, tm, ws, kmask, threadIdx.x);
}
__global__ void k_final_f(const unsigned* ws, float* out) {
    if (blockIdx.x == 0) final_body(ws, out, threadIdx.x);
}

extern "C" void kernel_launch(void* const* d_in, const int* in_sizes, int n_in,
                              void* d_out, int out_size, void* d_ws, size_t ws_size,
                              hipStream_t stream) {
    const float* pred = (const float*)d_in[0];
    const float* gt   = (const float*)d_in[1];
    const float* gtk  = (const float*)d_in[2];
    const float* tm   = (const float*)d_in[3];
    float* out = (float*)d_out;
    unsigned* ws = (unsigned*)d_ws;
    unsigned char* kmask = (unsigned char*)(ws + KMASK_OFF);

    void* args[] = { (void*)&pred, (void*)&gt, (void*)&gtk, (void*)&tm,
                     (void*)&ws, (void*)&kmask, (void*)&out };
    hipError_t e = hipLaunchCooperativeKernel((const void*)k_all, dim3(GRID), dim3(256),
                                              args, 0, stream);
    if (e != hipSuccess) {
        // Fallback: same phase bodies as discrete dispatches.
        hipMemsetAsync(ws, 0, (size_t)(HIST_WORDS + SMALL_WORDS) * 4, stream);
        k_prep_f<<<PREP_TILES, 256, 0, stream>>>(pred, gt, tm, ws, kmask);
        k_scan_f<<<BB, 256, 0, stream>>>(ws, 0);
        hipMemsetAsync(ws, 0, (size_t)HIST_WORDS * 4, stream);
        k_refine_f<<<PREP_TILES, 256, 0, stream>>>(pred, gt, ws);
        k_scan_f<<<BB, 256, 0, stream>>>(ws, 1);
        k_dice_f<<<DICE_TILES, 256, 0, stream>>>(pred, gt, gtk, tm, ws, kmask);
        k_final_f<<<1, 256, 0, stream>>>(ws, out);
    }
}